// Round 2
// baseline (310.773 us; speedup 1.0000x reference)
//
#include <hip/hip_runtime.h>
#include <math.h>

typedef unsigned long long u64;

// ---------------------------------------------------------------------------
// Kernel 1: KNN (bit-exact vs np/fp32 reference) + fused 3-scale surface conv.
// Keys: (monotone fp32 dist << 10) | idx (unique).
//  1) seed threshold T = wave-max of per-lane 2nd-smallest key (count>=127);
//     bisect tight range down to count <= 192.
//  2) compact candidates < T to LDS via wave prefix-scan
//  3) brute-force exact ranks (pairs via b128); rank 0 dropped,
//     ranks 1..100 -> slots 0..99
//  4) nd written (float4) to global AND LDS by rank; block then computes
//     surf_l/m/g (k=5/20/100 prefixes) for its 4 rows from LDS.
// One wave per row, 4 rows per 256-thread block. LDS ~22.7 KB.
// ---------------------------------------------------------------------------
__global__ __launch_bounds__(256) void knnsurf_kernel(
    const float* __restrict__ verts,
    int* __restrict__ idx_out, float4* __restrict__ nd_out,
    const float* __restrict__ dl, const float* __restrict__ dm,
    const float* __restrict__ dg,
    float* __restrict__ raw_l, float* __restrict__ raw_m, float* __restrict__ raw_g)
{
    __shared__ float4 vps[1024];                    // x,y,z,sq  (16 KB)
    __shared__ __align__(16) u64 cand[4][208];      // 6.7 KB; row = 16B-aligned
    const int tid = threadIdx.x;
    const int row0 = blockIdx.x * 4;
    const int b = row0 >> 10;            // block never crosses a batch
    const float* vb = verts + b * 3072;

    for (int n = tid; n < 1024; n += 256) {
        float x = vb[3 * n], y = vb[3 * n + 1], z = vb[3 * n + 2];
        float s = __fadd_rn(__fadd_rn(__fmul_rn(x, x), __fmul_rn(y, y)),
                            __fmul_rn(z, z));
        vps[n] = make_float4(x, y, z, s);
    }
    __syncthreads();

    const int w = tid >> 6, lane = tid & 63;
    const int row = row0 + w;
    const int n_i = row & 1023;
    const float4 pi = vps[n_i];
    const float xi = pi.x, yi = pi.y, zi = pi.z, sqi = pi.w;

    u64 K[16];
    u64 m1 = ~0ULL, m2 = ~0ULL;          // per-lane two smallest
#pragma unroll
    for (int t = 0; t < 16; ++t) {
        int j = t * 64 + lane;
        float4 p = vps[j];
        float dot = __fadd_rn(__fadd_rn(__fmul_rn(xi, p.x),
                                        __fmul_rn(yi, p.y)),
                              __fmul_rn(zi, p.z));
        float d = __fsub_rn(__fadd_rn(sqi, p.w), __fmul_rn(2.0f, dot));
        d = __fadd_rn(d, 0.0f);          // canonicalize -0.0 -> +0.0
        unsigned u = __float_as_uint(d);
        unsigned m = (u & 0x80000000u) ? ~u : (u | 0x80000000u);
        u64 k = ((u64)m << 10) | (unsigned)j;
        K[t] = k;
        bool lt1 = k < m1;
        u64 nm2 = lt1 ? m1 : ((k < m2) ? k : m2);
        m1 = lt1 ? k : m1;
        m2 = nm2;
    }

    // wave-max(m2) and wave-min(m1)
    u64 tmax = m2, tmin = m1;
#pragma unroll
    for (int off = 1; off < 64; off <<= 1) {
        u64 a = __shfl_xor(tmax, off); if (a > tmax) tmax = a;
        u64 c = __shfl_xor(tmin, off); if (c < tmin) tmin = c;
    }

    // count at T = tmax (guaranteed >= 127); bisect down to <= 192
    u64 T = tmax;
    int chi;
    {
        int c = 0;
#pragma unroll
        for (int t = 0; t < 16; ++t) c += (K[t] < T) ? 1 : 0;
#pragma unroll
        for (int off = 1; off < 64; off <<= 1) c += __shfl_xor(c, off);
        chi = c;
    }
    u64 lo = tmin, hi = T;
    while (chi > 192) {
        u64 mid = (lo + hi) >> 1;
        int c = 0;
#pragma unroll
        for (int t = 0; t < 16; ++t) c += (K[t] < mid) ? 1 : 0;
#pragma unroll
        for (int off = 1; off < 64; off <<= 1) c += __shfl_xor(c, off);
        if (c >= 101) { hi = mid; chi = c; } else lo = mid;
    }
    T = hi;
    const int n = chi;                   // 101 <= n <= 192

    // compact candidates < T via wave prefix-scan
    int myc_n = 0;
#pragma unroll
    for (int t = 0; t < 16; ++t) myc_n += (K[t] < T) ? 1 : 0;
    int sc = myc_n;
#pragma unroll
    for (int off = 1; off < 64; off <<= 1) {
        int v = __shfl_up(sc, off);
        if (lane >= off) sc += v;
    }
    int pos = sc - myc_n;
#pragma unroll
    for (int t = 0; t < 16; ++t) {
        if (K[t] < T) cand[w][pos++] = K[t];
    }
    if (lane == 0) cand[w][n] = ~0ULL;   // sentinel for b128 pair tail
    __syncthreads();

    // exact ranks within compacted set (pairs via b128)
    u64 myc[3]; int rk[3];
#pragma unroll
    for (int q = 0; q < 3; ++q) {
        int i = lane + q * 64;
        myc[q] = (i < n) ? cand[w][i] : ~0ULL;
        rk[q] = 0;
    }
    {
        const ulonglong2* c2 = (const ulonglong2*)&cand[w][0];
        const int half = (n + 1) >> 1;
        for (int jj = 0; jj < half; ++jj) {
            ulonglong2 kk = c2[jj];
#pragma unroll
            for (int q = 0; q < 3; ++q) {
                rk[q] += (kk.x < myc[q]) ? 1 : 0;
                rk[q] += (kk.y < myc[q]) ? 1 : 0;
            }
        }
    }

    // write ranks 1..100 (float4) to global AND LDS (aliasing cand[w] -
    // wave-private region; within-wave LDS ops are ordered)
    const int rowbase = row & ~1023;
    float4* nd4w = (float4*)&cand[w][0];
#pragma unroll
    for (int q = 0; q < 3; ++q) {
        int i = lane + q * 64;
        if (i < n) {
            int r = rk[q];
            if (r >= 1 && r <= 100) {
                int slot = r - 1;
                unsigned j = (unsigned)(myc[q] & 1023u);
                idx_out[row * 100 + slot] = rowbase + (int)j;
                float4 pj = vps[j];
                float dx = pj.x - xi, dy = pj.y - yi, dz = pj.z - zi;
                float nrm = sqrtf(__fadd_rn(__fadd_rn(__fmul_rn(dx, dx),
                                                      __fmul_rn(dy, dy)),
                                            __fmul_rn(dz, dz)));
                float inv = 1.0f / fmaxf(nrm, 1e-12f);
                float4 nv = make_float4(dx * inv, dy * inv, dz * inv, 0.0f);
                nd_out[row * 100 + slot] = nv;
                nd4w[slot] = nv;
            }
        }
    }
    __syncthreads();

    // ---- fused surface conv for the block's 4 rows ----
    const int d = tid & 127;
    float lx = dl[d], ly = dl[128 + d], lz = dl[256 + d];
    float li = 1.0f / fmaxf(sqrtf((lx * lx + ly * ly) + lz * lz), 1e-12f);
    lx *= li; ly *= li; lz *= li;
    float mx = dm[d], my = dm[128 + d], mz = dm[256 + d];
    float mi = 1.0f / fmaxf(sqrtf((mx * mx + my * my) + mz * mz), 1e-12f);
    mx *= mi; my *= mi; mz *= mi;
    float gx = dg[d], gy = dg[128 + d], gz = dg[256 + d];
    float gi = 1.0f / fmaxf(sqrtf((gx * gx + gy * gy) + gz * gz), 1e-12f);
    gx *= gi; gy *= gi; gz *= gi;

#pragma unroll
    for (int p = 0; p < 2; ++p) {
        int rr = (tid >> 7) + 2 * p;     // wave-uniform
        const float4* ns = (const float4*)&cand[rr][0];
        float ml = -1e30f, mm = -1e30f, mg = -1e30f;
        int k = 0;
        for (; k < 5; ++k) {
            float4 v = ns[k];
            ml = fmaxf(ml, (v.x * lx + v.y * ly) + v.z * lz);
            mm = fmaxf(mm, (v.x * mx + v.y * my) + v.z * mz);
            mg = fmaxf(mg, (v.x * gx + v.y * gy) + v.z * gz);
        }
        for (; k < 20; ++k) {
            float4 v = ns[k];
            mm = fmaxf(mm, (v.x * mx + v.y * my) + v.z * mz);
            mg = fmaxf(mg, (v.x * gx + v.y * gy) + v.z * gz);
        }
        for (; k < 100; ++k) {
            float4 v = ns[k];
            mg = fmaxf(mg, (v.x * gx + v.y * gy) + v.z * gz);
        }
        int orow = row0 + rr;
        raw_l[orow * 128 + d] = fmaxf(ml, 0.0f);
        raw_m[orow * 128 + d] = fmaxf(mm, 0.0f);
        raw_g[orow * 128 + d] = fmaxf(mg, 0.0f);
    }
}

// ---------------------------------------------------------------------------
// Kernel 2: BN partial sums: 32 blocks per tensor, 128 rows each, coalesced,
// fp64, deterministic. Layout: p[blk*256+c]=sum, p[blk*256+128+c]=sumsq.
// ---------------------------------------------------------------------------
__global__ __launch_bounds__(256) void bnsum_kernel(
    const float* s0, double* p0,
    const float* s1, double* p1,
    const float* s2, double* p2)
{
    const int t = blockIdx.x >> 5;
    const int blk = blockIdx.x & 31;
    const float* src = (t == 0) ? s0 : (t == 1) ? s1 : s2;
    double* p = (t == 0) ? p0 : (t == 1) ? p1 : p2;
    const int tid = threadIdx.x;
    const int c = tid & 127, seg = tid >> 7;    // 2 segs x 64 rows
    const float* q = src + ((size_t)blk * 128 + seg * 64) * 128 + c;
    double s = 0.0, ss = 0.0;
    for (int r = 0; r < 64; ++r) { float v = q[r * 128]; s += v; ss += (double)v * v; }
    __shared__ double Ls[2][128], Lq[2][128];
    Ls[seg][c] = s; Lq[seg][c] = ss;
    __syncthreads();
    if (tid < 128) {
        p[blk * 256 + c]       = Ls[0][c] + Ls[1][c];
        p[blk * 256 + 128 + c] = Lq[0][c] + Lq[1][c];
    }
}

// st from partials: a = g/sqrt(var+eps), b2 = e - m*a (fp64, deterministic)
__device__ __forceinline__ void compute_st(const double* __restrict__ p,
                                           const float* __restrict__ g,
                                           const float* __restrict__ e,
                                           float* stA, float* stB,
                                           int tid, int nthreads)
{
    for (int c = tid; c < 128; c += nthreads) {
        double S = 0.0, Q = 0.0;
#pragma unroll
        for (int bb = 0; bb < 32; ++bb) { S += p[bb * 256 + c]; Q += p[bb * 256 + 128 + c]; }
        double m = S * (1.0 / 4096.0);
        double var = Q * (1.0 / 4096.0) - m * m;
        double a = (double)g[c] / sqrt(var + 1e-5);
        stA[c] = (float)a;
        stB[c] = (float)((double)e[c] - m * a);
    }
}

// ---------------------------------------------------------------------------
// Kernel 2b: BN apply: dst[(row)*str + off + c] = relu(stA[c]*src + stB[c]).
// 16 rows per 256-thread block, up to 3 tensors via blockIdx.y. Values are
// bit-identical to the old in-GEMM LDS staging (same fp64 compute_st, same
// fmaxf(fmaf(...)) expression).
// ---------------------------------------------------------------------------
__global__ __launch_bounds__(256) void bnapply_kernel(
    const float* __restrict__ s0, const double* __restrict__ p0,
    const float* __restrict__ g0, const float* __restrict__ e0,
    float* __restrict__ d0, int str0, int off0,
    const float* __restrict__ s1, const double* __restrict__ p1,
    const float* __restrict__ g1, const float* __restrict__ e1,
    float* __restrict__ d1, int str1, int off1,
    const float* __restrict__ s2, const double* __restrict__ p2,
    const float* __restrict__ g2, const float* __restrict__ e2,
    float* __restrict__ d2, int str2, int off2)
{
    const int job = blockIdx.y;
    const float* src = (job == 0) ? s0 : (job == 1) ? s1 : s2;
    const double* p  = (job == 0) ? p0 : (job == 1) ? p1 : p2;
    const float* g   = (job == 0) ? g0 : (job == 1) ? g1 : g2;
    const float* e   = (job == 0) ? e0 : (job == 1) ? e1 : e2;
    float* dst       = (job == 0) ? d0 : (job == 1) ? d1 : d2;
    const int str    = (job == 0) ? str0 : (job == 1) ? str1 : str2;
    const int off    = (job == 0) ? off0 : (job == 1) ? off1 : off2;

    __shared__ float stA[128], stB[128];
    const int tid = threadIdx.x;
    compute_st(p, g, e, stA, stB, tid, 256);
    __syncthreads();

    const int r0 = blockIdx.x * 16;
    for (int t = tid; t < 16 * 128; t += 256) {
        int r = t >> 7, c = t & 127;
        float v = src[(size_t)(r0 + r) * 128 + c];
        dst[(size_t)(r0 + r) * str + off + c] =
            fmaxf(fmaf(stA[c], v, stB[c]), 0.0f);
    }
}

// ---------------------------------------------------------------------------
// Kernel 3: dual-job GEMM (CIN=128), 8 rows/block, 256 threads (o = col).
// A is pre-normalized (bnapply). A addresses are wave-uniform -> the compiler
// emits scalar loads (s_load_dwordx4): A rides the scalar pipe / constant
// cache and feeds v_fmac as the SGPR operand. W is the only vector-memory
// stream (coalesced, L2-resident). No LDS, no barriers.
// ---------------------------------------------------------------------------
__global__ __launch_bounds__(256) void gemm2_kernel(
    const float* __restrict__ Aa, const float* __restrict__ Wa,
    const float* __restrict__ ba, float* __restrict__ outa,
    const float* __restrict__ Ab, const float* __restrict__ Wb,
    const float* __restrict__ bb, float* __restrict__ outb)
{
    const int job = blockIdx.y;
    const float* __restrict__ A = job ? Ab : Aa;
    const float* __restrict__ W = job ? Wb : Wa;
    const float* __restrict__ bias = job ? bb : ba;
    float* __restrict__ out = job ? outb : outa;

    const int o = threadIdx.x;
    const int r0 = blockIdx.x * 8;
    const float* Wp = W + o;

    float acc[8];
    const float bz = bias[o];
#pragma unroll
    for (int r = 0; r < 8; ++r) acc[r] = bz;

    for (int c0 = 0; c0 < 128; c0 += 16) {
        float w[16];
#pragma unroll
        for (int q = 0; q < 16; ++q) w[q] = Wp[(c0 + q) * 256];
#pragma unroll
        for (int cc = 0; cc < 16; cc += 4) {
#pragma unroll
            for (int r = 0; r < 8; ++r) {
                const float4 a = *(const float4*)&A[(size_t)(r0 + r) * 128 + c0 + cc];
                acc[r] += a.x * w[cc] + a.y * w[cc + 1] + a.z * w[cc + 2] + a.w * w[cc + 3];
            }
        }
    }
#pragma unroll
    for (int r = 0; r < 8; ++r)
        out[(size_t)(r0 + r) * 256 + o] = acc[r];
}

// ---------------------------------------------------------------------------
// Kernel 4: conv-layer apply, 1 row per 128-thread block, up to 2 jobs via
// blockIdx.y. nd (float4) / idx reads wave-uniform -> scalar loads.
// ---------------------------------------------------------------------------
__global__ __launch_bounds__(128) void layer_kernel(
    const float4* __restrict__ nd, const int* __restrict__ idxbuf,
    const float* dir0, const float* fo0, float* out0, int K0,
    const float* dir1, const float* fo1, float* out1, int K1)
{
    const int job = blockIdx.y;
    const float* dirs = job ? dir1 : dir0;
    const float* fo = job ? fo1 : fo0;
    float* out = job ? out1 : out0;
    const int K = job ? K1 : K0;

    const int d = threadIdx.x;
    const int row = blockIdx.x;

    float dx = dirs[d], dy = dirs[128 + d], dz = dirs[256 + d];
    float di = 1.0f / fmaxf(sqrtf((dx * dx + dy * dy) + dz * dz), 1e-12f);
    dx *= di; dy *= di; dz *= di;

    const float4* ns = nd + (size_t)row * 100;
    const int* ib = idxbuf + (size_t)row * 100;

    float acc = -1e30f;
    for (int k = 0; k < K; ++k) {
        float4 v = ns[k];
        int ix = ib[k];
        float th = fmaxf((v.x * dx + v.y * dy) + v.z * dz, 0.0f);
        float fs = fo[ix * 256 + 128 + d];
        acc = fmaxf(acc, th * fs);
    }
    out[row * 128 + d] = fo[row * 256 + d] + acc;
}

// ---------------------------------------------------------------------------
// Kernel 5: final GEMM (CIN=384), 8 rows/block (grid 512), 256 threads,
// A pre-normalized concat [4096][384] via scalar loads, W via vector loads,
// final relu. No LDS.
// ---------------------------------------------------------------------------
__global__ __launch_bounds__(256) void gemmf_kernel(
    const float* __restrict__ A,
    const float* __restrict__ W, const float* __restrict__ bias,
    float* __restrict__ out)
{
    const int o = threadIdx.x;
    const int r0 = blockIdx.x * 8;
    const float* Wp = W + o;

    float acc[8];
    const float bz = bias[o];
#pragma unroll
    for (int r = 0; r < 8; ++r) acc[r] = bz;

    for (int c0 = 0; c0 < 384; c0 += 16) {
        float w[16];
#pragma unroll
        for (int q = 0; q < 16; ++q) w[q] = Wp[(c0 + q) * 256];
#pragma unroll
        for (int cc = 0; cc < 16; cc += 4) {
#pragma unroll
            for (int r = 0; r < 8; ++r) {
                const float4 a = *(const float4*)&A[(size_t)(r0 + r) * 384 + c0 + cc];
                acc[r] += a.x * w[cc] + a.y * w[cc + 1] + a.z * w[cc + 2] + a.w * w[cc + 3];
            }
        }
    }
#pragma unroll
    for (int r = 0; r < 8; ++r)
        out[(size_t)(r0 + r) * 256 + o] = fmaxf(acc[r], 0.0f);
}

// ---------------------------------------------------------------------------
extern "C" void kernel_launch(void* const* d_in, const int* in_sizes, int n_in,
                              void* d_out, int out_size, void* d_ws, size_t ws_size,
                              hipStream_t stream)
{
    (void)in_sizes; (void)n_in; (void)out_size; (void)ws_size;

    const float* verts   = (const float*)d_in[0];
    const float* dirs_l  = (const float*)d_in[1];
    const float* dirs_m0 = (const float*)d_in[2];
    const float* W_m1    = (const float*)d_in[3];
    const float* b_m1    = (const float*)d_in[4];
    const float* dirs_m1 = (const float*)d_in[5];
    const float* dirs_g0 = (const float*)d_in[6];
    const float* W_g1    = (const float*)d_in[7];
    const float* b_g1    = (const float*)d_in[8];
    const float* dirs_g1 = (const float*)d_in[9];
    const float* W_g2    = (const float*)d_in[10];
    const float* b_g2    = (const float*)d_in[11];
    const float* dirs_g2 = (const float*)d_in[12];
    const float* g_l  = (const float*)d_in[13]; const float* be_l  = (const float*)d_in[14];
    const float* g_m0 = (const float*)d_in[15]; const float* be_m0 = (const float*)d_in[16];
    const float* g_m1 = (const float*)d_in[17]; const float* be_m1 = (const float*)d_in[18];
    const float* g_g0 = (const float*)d_in[19]; const float* be_g0 = (const float*)d_in[20];
    const float* g_g1 = (const float*)d_in[21]; const float* be_g1 = (const float*)d_in[22];
    const float* g_g2 = (const float*)d_in[23]; const float* be_g2 = (const float*)d_in[24];
    const float* W_down = (const float*)d_in[25];
    const float* b_down = (const float*)d_in[26];

    char* ws = (char*)d_ws;
    const size_t MB = 1 << 20;
    int*    idx100 = (int*)   (ws + 0);               // 1.64 MB
    double* p_l    = (double*)(ws + 0x1A0000);        // 6 x 64 KB fp64 partials
    double* p_m0   = p_l  + 8192;
    double* p_m1   = p_m0 + 8192;
    double* p_g0   = p_m1 + 8192;
    double* p_g1   = p_g0 + 8192;
    double* p_g2   = p_g1 + 8192;
    float4* nd100  = (float4*)(ws + 2 * MB);          // 6.55 MB (stride-4)
    float* raw_l  = (float*)(ws +  9 * MB);           // 2 MB each
    float* raw_m0 = (float*)(ws + 11 * MB);
    float* raw_g0 = (float*)(ws + 13 * MB);
    float* raw_m1 = (float*)(ws + 15 * MB);
    float* raw_g1 = (float*)(ws + 17 * MB);
    float* raw_g2 = (float*)(ws + 19 * MB);
    float* fo_m   = (float*)(ws + 21 * MB);           // 4 MB each
    float* fo_g   = (float*)(ws + 25 * MB);
    float* fo_g2  = (float*)(ws + 29 * MB);
    float* An_f   = (float*)(ws + 34 * MB);           // 4096 x 384 (6.3 MB)
    float* An_m0  = (float*)(ws + 41 * MB);           // 2 MB each
    float* An_g0  = (float*)(ws + 43 * MB);
    float* An_g1  = (float*)(ws + 45 * MB);

    // L1. KNN + nd + fused surface convs (k=5/20/100)
    knnsurf_kernel<<<1024, 256, 0, stream>>>(verts, idx100, nd100,
                                             dirs_l, dirs_m0, dirs_g0,
                                             raw_l, raw_m0, raw_g0);
    // L2. BN partials for l, m0, g0
    bnsum_kernel<<<96, 256, 0, stream>>>(raw_l, p_l, raw_m0, p_m0, raw_g0, p_g0);
    // L2b. apply BN: raw_l -> An_f[:,0:128]; raw_m0 -> An_m0; raw_g0 -> An_g0
    bnapply_kernel<<<dim3(256, 3), 256, 0, stream>>>(
        raw_l,  p_l,  g_l,  be_l,  An_f,  384, 0,
        raw_m0, p_m0, g_m0, be_m0, An_m0, 128, 0,
        raw_g0, p_g0, g_g0, be_g0, An_g0, 128, 0);
    // L3. fo_m = An_m0 @ W_m1 ; fo_g = An_g0 @ W_g1
    gemm2_kernel<<<dim3(512, 2), 256, 0, stream>>>(
        An_m0, W_m1, b_m1, fo_m,
        An_g0, W_g1, b_g1, fo_g);
    // L4. conv-layer apply (m1: K=20, g1: K=100)
    layer_kernel<<<dim3(4096, 2), 128, 0, stream>>>(nd100, idx100,
                                                    dirs_m1, fo_m, raw_m1, 20,
                                                    dirs_g1, fo_g, raw_g1, 100);
    // L5. BN partials for m1, g1
    bnsum_kernel<<<64, 256, 0, stream>>>(raw_m1, p_m1, raw_g1, p_g1, raw_g1, p_g1);
    // L5b. apply BN: raw_m1 -> An_f[:,128:256]; raw_g1 -> An_g1
    bnapply_kernel<<<dim3(256, 2), 256, 0, stream>>>(
        raw_m1, p_m1, g_m1, be_m1, An_f,  384, 128,
        raw_g1, p_g1, g_g1, be_g1, An_g1, 128, 0,
        raw_g1, p_g1, g_g1, be_g1, An_g1, 128, 0);
    // L6. fo_g2 = An_g1 @ W_g2
    gemm2_kernel<<<dim3(512, 1), 256, 0, stream>>>(
        An_g1, W_g2, b_g2, fo_g2,
        An_g1, W_g2, b_g2, fo_g2);
    // L7. conv-layer apply (g2: K=100)
    layer_kernel<<<dim3(4096, 1), 128, 0, stream>>>(nd100, idx100,
                                                    dirs_g2, fo_g2, raw_g2, 100,
                                                    dirs_g2, fo_g2, raw_g2, 100);
    // L8. BN partials for g2
    bnsum_kernel<<<32, 256, 0, stream>>>(raw_g2, p_g2, raw_g2, p_g2, raw_g2, p_g2);
    // L8b. apply BN: raw_g2 -> An_f[:,256:384]
    bnapply_kernel<<<dim3(256, 1), 256, 0, stream>>>(
        raw_g2, p_g2, g_g2, be_g2, An_f, 384, 256,
        raw_g2, p_g2, g_g2, be_g2, An_f, 384, 256,
        raw_g2, p_g2, g_g2, be_g2, An_f, 384, 256);
    // L9. final: relu(An_f @ W_down + b_down) -> fp32 out
    gemmf_kernel<<<512, 256, 0, stream>>>(An_f, W_down, b_down, (float*)d_out);
}

// Round 3
// 290.833 us; speedup vs baseline: 1.0686x; 1.0686x over previous
//
#include <hip/hip_runtime.h>
#include <math.h>

typedef unsigned long long u64;

// ---------------------------------------------------------------------------
// Kernel 1: KNN (bit-exact vs np/fp32 reference) + fused 3-scale surface conv.
// Keys: (monotone fp32 dist << 10) | idx (unique).
//  1) seed threshold T = wave-max of per-lane 2nd-smallest key (count>=127);
//     bisect tight range down to count <= 192.
//  2) compact candidates < T to LDS via wave prefix-scan
//  3) brute-force exact ranks (pairs via b128); rank 0 dropped,
//     ranks 1..100 -> slots 0..99
//  4) nd written (float4) to global AND LDS by rank; block then computes
//     surf_l/m/g (k=5/20/100 prefixes) for its 4 rows from LDS.
// One wave per row, 4 rows per 256-thread block. LDS ~22.7 KB.
// ---------------------------------------------------------------------------
__global__ __launch_bounds__(256) void knnsurf_kernel(
    const float* __restrict__ verts,
    int* __restrict__ idx_out, float4* __restrict__ nd_out,
    const float* __restrict__ dl, const float* __restrict__ dm,
    const float* __restrict__ dg,
    float* __restrict__ raw_l, float* __restrict__ raw_m, float* __restrict__ raw_g)
{
    __shared__ float4 vps[1024];                    // x,y,z,sq  (16 KB)
    __shared__ __align__(16) u64 cand[4][208];      // 6.7 KB; row = 16B-aligned
    const int tid = threadIdx.x;
    const int row0 = blockIdx.x * 4;
    const int b = row0 >> 10;            // block never crosses a batch
    const float* vb = verts + b * 3072;

    for (int n = tid; n < 1024; n += 256) {
        float x = vb[3 * n], y = vb[3 * n + 1], z = vb[3 * n + 2];
        float s = __fadd_rn(__fadd_rn(__fmul_rn(x, x), __fmul_rn(y, y)),
                            __fmul_rn(z, z));
        vps[n] = make_float4(x, y, z, s);
    }
    __syncthreads();

    const int w = tid >> 6, lane = tid & 63;
    const int row = row0 + w;
    const int n_i = row & 1023;
    const float4 pi = vps[n_i];
    const float xi = pi.x, yi = pi.y, zi = pi.z, sqi = pi.w;

    u64 K[16];
    u64 m1 = ~0ULL, m2 = ~0ULL;          // per-lane two smallest
#pragma unroll
    for (int t = 0; t < 16; ++t) {
        int j = t * 64 + lane;
        float4 p = vps[j];
        float dot = __fadd_rn(__fadd_rn(__fmul_rn(xi, p.x),
                                        __fmul_rn(yi, p.y)),
                              __fmul_rn(zi, p.z));
        float d = __fsub_rn(__fadd_rn(sqi, p.w), __fmul_rn(2.0f, dot));
        d = __fadd_rn(d, 0.0f);          // canonicalize -0.0 -> +0.0
        unsigned u = __float_as_uint(d);
        unsigned m = (u & 0x80000000u) ? ~u : (u | 0x80000000u);
        u64 k = ((u64)m << 10) | (unsigned)j;
        K[t] = k;
        bool lt1 = k < m1;
        u64 nm2 = lt1 ? m1 : ((k < m2) ? k : m2);
        m1 = lt1 ? k : m1;
        m2 = nm2;
    }

    // wave-max(m2) and wave-min(m1)
    u64 tmax = m2, tmin = m1;
#pragma unroll
    for (int off = 1; off < 64; off <<= 1) {
        u64 a = __shfl_xor(tmax, off); if (a > tmax) tmax = a;
        u64 c = __shfl_xor(tmin, off); if (c < tmin) tmin = c;
    }

    // count at T = tmax (guaranteed >= 127); bisect down to <= 192
    u64 T = tmax;
    int chi;
    {
        int c = 0;
#pragma unroll
        for (int t = 0; t < 16; ++t) c += (K[t] < T) ? 1 : 0;
#pragma unroll
        for (int off = 1; off < 64; off <<= 1) c += __shfl_xor(c, off);
        chi = c;
    }
    u64 lo = tmin, hi = T;
    while (chi > 192) {
        u64 mid = (lo + hi) >> 1;
        int c = 0;
#pragma unroll
        for (int t = 0; t < 16; ++t) c += (K[t] < mid) ? 1 : 0;
#pragma unroll
        for (int off = 1; off < 64; off <<= 1) c += __shfl_xor(c, off);
        if (c >= 101) { hi = mid; chi = c; } else lo = mid;
    }
    T = hi;
    const int n = chi;                   // 101 <= n <= 192

    // compact candidates < T via wave prefix-scan
    int myc_n = 0;
#pragma unroll
    for (int t = 0; t < 16; ++t) myc_n += (K[t] < T) ? 1 : 0;
    int sc = myc_n;
#pragma unroll
    for (int off = 1; off < 64; off <<= 1) {
        int v = __shfl_up(sc, off);
        if (lane >= off) sc += v;
    }
    int pos = sc - myc_n;
#pragma unroll
    for (int t = 0; t < 16; ++t) {
        if (K[t] < T) cand[w][pos++] = K[t];
    }
    if (lane == 0) cand[w][n] = ~0ULL;   // sentinel for b128 pair tail
    __syncthreads();

    // exact ranks within compacted set (pairs via b128)
    u64 myc[3]; int rk[3];
#pragma unroll
    for (int q = 0; q < 3; ++q) {
        int i = lane + q * 64;
        myc[q] = (i < n) ? cand[w][i] : ~0ULL;
        rk[q] = 0;
    }
    {
        const ulonglong2* c2 = (const ulonglong2*)&cand[w][0];
        const int half = (n + 1) >> 1;
        for (int jj = 0; jj < half; ++jj) {
            ulonglong2 kk = c2[jj];
#pragma unroll
            for (int q = 0; q < 3; ++q) {
                rk[q] += (kk.x < myc[q]) ? 1 : 0;
                rk[q] += (kk.y < myc[q]) ? 1 : 0;
            }
        }
    }

    // write ranks 1..100 (float4) to global AND LDS (aliasing cand[w] -
    // wave-private region; within-wave LDS ops are ordered)
    const int rowbase = row & ~1023;
    float4* nd4w = (float4*)&cand[w][0];
#pragma unroll
    for (int q = 0; q < 3; ++q) {
        int i = lane + q * 64;
        if (i < n) {
            int r = rk[q];
            if (r >= 1 && r <= 100) {
                int slot = r - 1;
                unsigned j = (unsigned)(myc[q] & 1023u);
                idx_out[row * 100 + slot] = rowbase + (int)j;
                float4 pj = vps[j];
                float dx = pj.x - xi, dy = pj.y - yi, dz = pj.z - zi;
                float nrm = sqrtf(__fadd_rn(__fadd_rn(__fmul_rn(dx, dx),
                                                      __fmul_rn(dy, dy)),
                                            __fmul_rn(dz, dz)));
                float inv = 1.0f / fmaxf(nrm, 1e-12f);
                float4 nv = make_float4(dx * inv, dy * inv, dz * inv, 0.0f);
                nd_out[row * 100 + slot] = nv;
                nd4w[slot] = nv;
            }
        }
    }
    __syncthreads();

    // ---- fused surface conv for the block's 4 rows ----
    const int d = tid & 127;
    float lx = dl[d], ly = dl[128 + d], lz = dl[256 + d];
    float li = 1.0f / fmaxf(sqrtf((lx * lx + ly * ly) + lz * lz), 1e-12f);
    lx *= li; ly *= li; lz *= li;
    float mx = dm[d], my = dm[128 + d], mz = dm[256 + d];
    float mi = 1.0f / fmaxf(sqrtf((mx * mx + my * my) + mz * mz), 1e-12f);
    mx *= mi; my *= mi; mz *= mi;
    float gx = dg[d], gy = dg[128 + d], gz = dg[256 + d];
    float gi = 1.0f / fmaxf(sqrtf((gx * gx + gy * gy) + gz * gz), 1e-12f);
    gx *= gi; gy *= gi; gz *= gi;

#pragma unroll
    for (int p = 0; p < 2; ++p) {
        int rr = (tid >> 7) + 2 * p;     // wave-uniform
        const float4* ns = (const float4*)&cand[rr][0];
        float ml = -1e30f, mm = -1e30f, mg = -1e30f;
        int k = 0;
        for (; k < 5; ++k) {
            float4 v = ns[k];
            ml = fmaxf(ml, (v.x * lx + v.y * ly) + v.z * lz);
            mm = fmaxf(mm, (v.x * mx + v.y * my) + v.z * mz);
            mg = fmaxf(mg, (v.x * gx + v.y * gy) + v.z * gz);
        }
        for (; k < 20; ++k) {
            float4 v = ns[k];
            mm = fmaxf(mm, (v.x * mx + v.y * my) + v.z * mz);
            mg = fmaxf(mg, (v.x * gx + v.y * gy) + v.z * gz);
        }
        for (; k < 100; ++k) {
            float4 v = ns[k];
            mg = fmaxf(mg, (v.x * gx + v.y * gy) + v.z * gz);
        }
        int orow = row0 + rr;
        raw_l[orow * 128 + d] = fmaxf(ml, 0.0f);
        raw_m[orow * 128 + d] = fmaxf(mm, 0.0f);
        raw_g[orow * 128 + d] = fmaxf(mg, 0.0f);
    }
}

// ---------------------------------------------------------------------------
// Kernel 2: BN partial sums: 32 blocks per tensor, 128 rows each, coalesced,
// fp64, deterministic. Layout: p[blk*256+c]=sum, p[blk*256+128+c]=sumsq.
// ---------------------------------------------------------------------------
__global__ __launch_bounds__(256) void bnsum_kernel(
    const float* s0, double* p0,
    const float* s1, double* p1,
    const float* s2, double* p2)
{
    const int t = blockIdx.x >> 5;
    const int blk = blockIdx.x & 31;
    const float* src = (t == 0) ? s0 : (t == 1) ? s1 : s2;
    double* p = (t == 0) ? p0 : (t == 1) ? p1 : p2;
    const int tid = threadIdx.x;
    const int c = tid & 127, seg = tid >> 7;    // 2 segs x 64 rows
    const float* q = src + ((size_t)blk * 128 + seg * 64) * 128 + c;
    double s = 0.0, ss = 0.0;
    for (int r = 0; r < 64; ++r) { float v = q[r * 128]; s += v; ss += (double)v * v; }
    __shared__ double Ls[2][128], Lq[2][128];
    Ls[seg][c] = s; Lq[seg][c] = ss;
    __syncthreads();
    if (tid < 128) {
        p[blk * 256 + c]       = Ls[0][c] + Ls[1][c];
        p[blk * 256 + 128 + c] = Lq[0][c] + Lq[1][c];
    }
}

// st from partials: a = g/sqrt(var+eps), b2 = e - m*a (fp64, deterministic)
__device__ __forceinline__ void compute_st(const double* __restrict__ p,
                                           const float* __restrict__ g,
                                           const float* __restrict__ e,
                                           float* stA, float* stB,
                                           int tid, int nthreads)
{
    for (int c = tid; c < 128; c += nthreads) {
        double S = 0.0, Q = 0.0;
#pragma unroll
        for (int bb = 0; bb < 32; ++bb) { S += p[bb * 256 + c]; Q += p[bb * 256 + 128 + c]; }
        double m = S * (1.0 / 4096.0);
        double var = Q * (1.0 / 4096.0) - m * m;
        double a = (double)g[c] / sqrt(var + 1e-5);
        stA[c] = (float)a;
        stB[c] = (float)((double)e[c] - m * a);
    }
}

// ---------------------------------------------------------------------------
// Kernel 3: dual-job GEMM (CIN=128), 2D-tiled: 32 rows x 64 cols per block,
// 256 threads = 4 rowgroups x 64 cols, 8 rows x 1 col per thread.
// Each W element feeds 32 rows (4x less W traffic than 8-row tiles, the
// measured wall). BN applied during LDS staging (fp64 compute_st, same
// expression/order as before -> bit-identical). As reads in the MAC loop are
// wave-uniform broadcasts (conflict-free).
// grid: (rowtiles=128, coltiles=4, jobs).
// ---------------------------------------------------------------------------
__global__ __launch_bounds__(256) void gemm2_kernel(
    const float* __restrict__ Aa, const double* __restrict__ pa,
    const float* __restrict__ ga, const float* __restrict__ ea,
    const float* __restrict__ Wa, const float* __restrict__ ba, float* __restrict__ outa,
    const float* __restrict__ Ab, const double* __restrict__ pb,
    const float* __restrict__ gb, const float* __restrict__ eb,
    const float* __restrict__ Wb, const float* __restrict__ bb, float* __restrict__ outb)
{
    const int job = blockIdx.z;
    const float* __restrict__ A = job ? Ab : Aa;
    const double* __restrict__ p = job ? pb : pa;
    const float* __restrict__ g = job ? gb : ga;
    const float* __restrict__ e = job ? eb : ea;
    const float* __restrict__ W = job ? Wb : Wa;
    const float* __restrict__ bias = job ? bb : ba;
    float* __restrict__ out = job ? outb : outa;

    __shared__ float stA[128], stB[128];
    __shared__ float As[32 * 128];               // 16 KB
    const int tid = threadIdx.x;
    const int r0 = blockIdx.x * 32;

    compute_st(p, g, e, stA, stB, tid, 256);
    __syncthreads();

    // stage 32x128 BN-applied rows, float4-vectorized
    {
        const float4* A4 = (const float4*)(A + (size_t)r0 * 128);
        float4* As4 = (float4*)As;
        for (int t = tid; t < 32 * 32; t += 256) {
            int r = t >> 5, c4 = t & 31;
            float4 v = A4[r * 32 + c4];
            int c = c4 * 4;
            float4 o4;
            o4.x = fmaxf(fmaf(stA[c + 0], v.x, stB[c + 0]), 0.0f);
            o4.y = fmaxf(fmaf(stA[c + 1], v.y, stB[c + 1]), 0.0f);
            o4.z = fmaxf(fmaf(stA[c + 2], v.z, stB[c + 2]), 0.0f);
            o4.w = fmaxf(fmaf(stA[c + 3], v.w, stB[c + 3]), 0.0f);
            As4[t] = o4;
        }
    }
    __syncthreads();

    const int o = tid & 63;              // col within tile
    const int h = tid >> 6;              // rowgroup: rows h*8 .. h*8+7
    const int gcol = blockIdx.y * 64 + o;
    const float* Wp = W + gcol;

    float acc[8];
    const float bz = bias[gcol];
#pragma unroll
    for (int r = 0; r < 8; ++r) acc[r] = bz;

    for (int c0 = 0; c0 < 128; c0 += 16) {
        float w[16];
#pragma unroll
        for (int q = 0; q < 16; ++q) w[q] = Wp[(c0 + q) * 256];
#pragma unroll
        for (int cc = 0; cc < 16; cc += 4) {
#pragma unroll
            for (int r = 0; r < 8; ++r) {
                const float4 a = *(const float4*)&As[(h * 8 + r) * 128 + c0 + cc];
                acc[r] += a.x * w[cc] + a.y * w[cc + 1] + a.z * w[cc + 2] + a.w * w[cc + 3];
            }
        }
    }
#pragma unroll
    for (int r = 0; r < 8; ++r)
        out[(size_t)(r0 + h * 8 + r) * 256 + gcol] = acc[r];
}

// ---------------------------------------------------------------------------
// Kernel 4: conv-layer apply, 1 row per 128-thread block, up to 2 jobs via
// blockIdx.y. nd (float4) / idx reads wave-uniform -> scalar loads.
// ---------------------------------------------------------------------------
__global__ __launch_bounds__(128) void layer_kernel(
    const float4* __restrict__ nd, const int* __restrict__ idxbuf,
    const float* dir0, const float* fo0, float* out0, int K0,
    const float* dir1, const float* fo1, float* out1, int K1)
{
    const int job = blockIdx.y;
    const float* dirs = job ? dir1 : dir0;
    const float* fo = job ? fo1 : fo0;
    float* out = job ? out1 : out0;
    const int K = job ? K1 : K0;

    const int d = threadIdx.x;
    const int row = blockIdx.x;

    float dx = dirs[d], dy = dirs[128 + d], dz = dirs[256 + d];
    float di = 1.0f / fmaxf(sqrtf((dx * dx + dy * dy) + dz * dz), 1e-12f);
    dx *= di; dy *= di; dz *= di;

    const float4* ns = nd + (size_t)row * 100;
    const int* ib = idxbuf + (size_t)row * 100;

    float acc = -1e30f;
    for (int k = 0; k < K; ++k) {
        float4 v = ns[k];
        int ix = ib[k];
        float th = fmaxf((v.x * dx + v.y * dy) + v.z * dz, 0.0f);
        float fs = fo[ix * 256 + 128 + d];
        acc = fmaxf(acc, th * fs);
    }
    out[row * 128 + d] = fo[row * 256 + d] + acc;
}

// ---------------------------------------------------------------------------
// Kernel 5: final GEMM (CIN=384), 2D-tiled: 32 rows x 64 cols per block,
// 256 threads, 8 rows x 1 col per thread. BN affines for 3 segments derived
// in-kernel; staging float4-vectorized; final relu.
// grid: (rowtiles=128, coltiles=4). LDS 48K + 3K.
// ---------------------------------------------------------------------------
__global__ __launch_bounds__(256) void gemmf_kernel(
    const float* __restrict__ A0, const double* __restrict__ p0,
    const float* __restrict__ g0, const float* __restrict__ e0,
    const float* __restrict__ A1, const double* __restrict__ p1,
    const float* __restrict__ g1, const float* __restrict__ e1,
    const float* __restrict__ A2, const double* __restrict__ p2,
    const float* __restrict__ g2, const float* __restrict__ e2,
    const float* __restrict__ W, const float* __restrict__ bias, float* __restrict__ out)
{
    __shared__ float stA[384], stB[384];
    __shared__ float As[32 * 384];               // 48 KB
    const int tid = threadIdx.x;
    const int r0 = blockIdx.x * 32;

    compute_st(p0, g0, e0, stA,       stB,       tid, 256);
    compute_st(p1, g1, e1, stA + 128, stB + 128, tid, 256);
    compute_st(p2, g2, e2, stA + 256, stB + 256, tid, 256);
    __syncthreads();

    // stage 32x384 BN-applied rows, float4-vectorized (96 float4 per row)
    {
        float4* As4 = (float4*)As;
        for (int t = tid; t < 32 * 96; t += 256) {
            int r = t / 96, c4 = t - r * 96;
            int seg = c4 >> 5, cc4 = c4 & 31;
            const float* A = (seg == 0) ? A0 : (seg == 1) ? A1 : A2;
            float4 v = *(const float4*)&A[((size_t)(r0 + r) * 32 + cc4) * 4];
            int c = c4 * 4;
            float4 o4;
            o4.x = fmaxf(fmaf(stA[c + 0], v.x, stB[c + 0]), 0.0f);
            o4.y = fmaxf(fmaf(stA[c + 1], v.y, stB[c + 1]), 0.0f);
            o4.z = fmaxf(fmaf(stA[c + 2], v.z, stB[c + 2]), 0.0f);
            o4.w = fmaxf(fmaf(stA[c + 3], v.w, stB[c + 3]), 0.0f);
            As4[t] = o4;
        }
    }
    __syncthreads();

    const int o = tid & 63;
    const int h = tid >> 6;
    const int gcol = blockIdx.y * 64 + o;
    const float* Wp = W + gcol;

    float acc[8];
    const float bz = bias[gcol];
#pragma unroll
    for (int r = 0; r < 8; ++r) acc[r] = bz;

    for (int c0 = 0; c0 < 384; c0 += 16) {
        float w[16];
#pragma unroll
        for (int q = 0; q < 16; ++q) w[q] = Wp[(c0 + q) * 256];
#pragma unroll
        for (int cc = 0; cc < 16; cc += 4) {
#pragma unroll
            for (int r = 0; r < 8; ++r) {
                const float4 a = *(const float4*)&As[(h * 8 + r) * 384 + c0 + cc];
                acc[r] += a.x * w[cc] + a.y * w[cc + 1] + a.z * w[cc + 2] + a.w * w[cc + 3];
            }
        }
    }
#pragma unroll
    for (int r = 0; r < 8; ++r)
        out[(size_t)(r0 + h * 8 + r) * 256 + gcol] = fmaxf(acc[r], 0.0f);
}

// ---------------------------------------------------------------------------
extern "C" void kernel_launch(void* const* d_in, const int* in_sizes, int n_in,
                              void* d_out, int out_size, void* d_ws, size_t ws_size,
                              hipStream_t stream)
{
    (void)in_sizes; (void)n_in; (void)out_size; (void)ws_size;

    const float* verts   = (const float*)d_in[0];
    const float* dirs_l  = (const float*)d_in[1];
    const float* dirs_m0 = (const float*)d_in[2];
    const float* W_m1    = (const float*)d_in[3];
    const float* b_m1    = (const float*)d_in[4];
    const float* dirs_m1 = (const float*)d_in[5];
    const float* dirs_g0 = (const float*)d_in[6];
    const float* W_g1    = (const float*)d_in[7];
    const float* b_g1    = (const float*)d_in[8];
    const float* dirs_g1 = (const float*)d_in[9];
    const float* W_g2    = (const float*)d_in[10];
    const float* b_g2    = (const float*)d_in[11];
    const float* dirs_g2 = (const float*)d_in[12];
    const float* g_l  = (const float*)d_in[13]; const float* be_l  = (const float*)d_in[14];
    const float* g_m0 = (const float*)d_in[15]; const float* be_m0 = (const float*)d_in[16];
    const float* g_m1 = (const float*)d_in[17]; const float* be_m1 = (const float*)d_in[18];
    const float* g_g0 = (const float*)d_in[19]; const float* be_g0 = (const float*)d_in[20];
    const float* g_g1 = (const float*)d_in[21]; const float* be_g1 = (const float*)d_in[22];
    const float* g_g2 = (const float*)d_in[23]; const float* be_g2 = (const float*)d_in[24];
    const float* W_down = (const float*)d_in[25];
    const float* b_down = (const float*)d_in[26];

    char* ws = (char*)d_ws;
    const size_t MB = 1 << 20;
    int*    idx100 = (int*)   (ws + 0);               // 1.64 MB
    double* p_l    = (double*)(ws + 0x1A0000);        // 6 x 64 KB fp64 partials
    double* p_m0   = p_l  + 8192;
    double* p_m1   = p_m0 + 8192;
    double* p_g0   = p_m1 + 8192;
    double* p_g1   = p_g0 + 8192;
    double* p_g2   = p_g1 + 8192;
    float4* nd100  = (float4*)(ws + 2 * MB);          // 6.55 MB (stride-4)
    float* raw_l  = (float*)(ws +  9 * MB);           // 2 MB each
    float* raw_m0 = (float*)(ws + 11 * MB);
    float* raw_g0 = (float*)(ws + 13 * MB);
    float* raw_m1 = (float*)(ws + 15 * MB);
    float* raw_g1 = (float*)(ws + 17 * MB);
    float* raw_g2 = (float*)(ws + 19 * MB);
    float* fo_m   = (float*)(ws + 21 * MB);           // 4 MB each
    float* fo_g   = (float*)(ws + 25 * MB);
    float* fo_g2  = (float*)(ws + 29 * MB);

    // L1. KNN + nd + fused surface convs (k=5/20/100)
    knnsurf_kernel<<<1024, 256, 0, stream>>>(verts, idx100, nd100,
                                             dirs_l, dirs_m0, dirs_g0,
                                             raw_l, raw_m0, raw_g0);
    // L2. BN partials for l, m0, g0
    bnsum_kernel<<<96, 256, 0, stream>>>(raw_l, p_l, raw_m0, p_m0, raw_g0, p_g0);
    // L3. fo_m = bn_relu(raw_m0) @ W_m1 ; fo_g = bn_relu(raw_g0) @ W_g1
    gemm2_kernel<<<dim3(128, 4, 2), 256, 0, stream>>>(
        raw_m0, p_m0, g_m0, be_m0, W_m1, b_m1, fo_m,
        raw_g0, p_g0, g_g0, be_g0, W_g1, b_g1, fo_g);
    // L4. conv-layer apply (m1: K=20, g1: K=100)
    layer_kernel<<<dim3(4096, 2), 128, 0, stream>>>(nd100, idx100,
                                                    dirs_m1, fo_m, raw_m1, 20,
                                                    dirs_g1, fo_g, raw_g1, 100);
    // L5. BN partials for m1, g1
    bnsum_kernel<<<64, 256, 0, stream>>>(raw_m1, p_m1, raw_g1, p_g1, raw_g1, p_g1);
    // L6. fo_g2 = bn_relu(raw_g1) @ W_g2
    gemm2_kernel<<<dim3(128, 4, 1), 256, 0, stream>>>(
        raw_g1, p_g1, g_g1, be_g1, W_g2, b_g2, fo_g2,
        raw_g1, p_g1, g_g1, be_g1, W_g2, b_g2, fo_g2);
    // L7. conv-layer apply (g2: K=100)
    layer_kernel<<<dim3(4096, 1), 128, 0, stream>>>(nd100, idx100,
                                                    dirs_g2, fo_g2, raw_g2, 100,
                                                    dirs_g2, fo_g2, raw_g2, 100);
    // L8. BN partials for g2
    bnsum_kernel<<<32, 256, 0, stream>>>(raw_g2, p_g2, raw_g2, p_g2, raw_g2, p_g2);
    // L9. final: relu(concat(bn_relu each) @ W_down + b_down) -> fp32 out
    gemmf_kernel<<<dim3(128, 4), 256, 0, stream>>>(raw_l, p_l, g_l, be_l,
                                                   raw_m1, p_m1, g_m1, be_m1,
                                                   raw_g2, p_g2, g_g2, be_g2,
                                                   W_down, b_down, (float*)d_out);
}

// Round 4
// 282.010 us; speedup vs baseline: 1.1020x; 1.0313x over previous
//
#include <hip/hip_runtime.h>
#include <math.h>

typedef unsigned long long u64;

// ---------------------------------------------------------------------------
// Kernel 1: KNN (bit-exact vs np/fp32 reference) + fused 3-scale surface conv.
// Keys: (monotone fp32 dist << 10) | idx (unique).
//  1) seed threshold T = wave-max of per-lane 2nd-smallest key (count>=127);
//     bisect tight range down to count <= 192.
//  2) compact candidates < T to LDS via wave prefix-scan
//  3) brute-force exact ranks (pairs via b128); rank 0 dropped,
//     ranks 1..100 -> slots 0..99
//  4) nd written (float4) to global AND LDS by rank; block then computes
//     surf_l/m/g (k=5/20/100 prefixes) for its 4 rows from LDS.
// One wave per row, 4 rows per 256-thread block. LDS ~22.7 KB.
// ---------------------------------------------------------------------------
__global__ __launch_bounds__(256) void knnsurf_kernel(
    const float* __restrict__ verts,
    int* __restrict__ idx_out, float4* __restrict__ nd_out,
    const float* __restrict__ dl, const float* __restrict__ dm,
    const float* __restrict__ dg,
    float* __restrict__ raw_l, float* __restrict__ raw_m, float* __restrict__ raw_g)
{
    __shared__ float4 vps[1024];                    // x,y,z,sq  (16 KB)
    __shared__ __align__(16) u64 cand[4][208];      // 6.7 KB; row = 16B-aligned
    const int tid = threadIdx.x;
    const int row0 = blockIdx.x * 4;
    const int b = row0 >> 10;            // block never crosses a batch
    const float* vb = verts + b * 3072;

    for (int n = tid; n < 1024; n += 256) {
        float x = vb[3 * n], y = vb[3 * n + 1], z = vb[3 * n + 2];
        float s = __fadd_rn(__fadd_rn(__fmul_rn(x, x), __fmul_rn(y, y)),
                            __fmul_rn(z, z));
        vps[n] = make_float4(x, y, z, s);
    }
    __syncthreads();

    const int w = tid >> 6, lane = tid & 63;
    const int row = row0 + w;
    const int n_i = row & 1023;
    const float4 pi = vps[n_i];
    const float xi = pi.x, yi = pi.y, zi = pi.z, sqi = pi.w;

    u64 K[16];
    u64 m1 = ~0ULL, m2 = ~0ULL;          // per-lane two smallest
#pragma unroll
    for (int t = 0; t < 16; ++t) {
        int j = t * 64 + lane;
        float4 p = vps[j];
        float dot = __fadd_rn(__fadd_rn(__fmul_rn(xi, p.x),
                                        __fmul_rn(yi, p.y)),
                              __fmul_rn(zi, p.z));
        float d = __fsub_rn(__fadd_rn(sqi, p.w), __fmul_rn(2.0f, dot));
        d = __fadd_rn(d, 0.0f);          // canonicalize -0.0 -> +0.0
        unsigned u = __float_as_uint(d);
        unsigned m = (u & 0x80000000u) ? ~u : (u | 0x80000000u);
        u64 k = ((u64)m << 10) | (unsigned)j;
        K[t] = k;
        bool lt1 = k < m1;
        u64 nm2 = lt1 ? m1 : ((k < m2) ? k : m2);
        m1 = lt1 ? k : m1;
        m2 = nm2;
    }

    // wave-max(m2) and wave-min(m1)
    u64 tmax = m2, tmin = m1;
#pragma unroll
    for (int off = 1; off < 64; off <<= 1) {
        u64 a = __shfl_xor(tmax, off); if (a > tmax) tmax = a;
        u64 c = __shfl_xor(tmin, off); if (c < tmin) tmin = c;
    }

    // count at T = tmax (guaranteed >= 127); bisect down to <= 192
    u64 T = tmax;
    int chi;
    {
        int c = 0;
#pragma unroll
        for (int t = 0; t < 16; ++t) c += (K[t] < T) ? 1 : 0;
#pragma unroll
        for (int off = 1; off < 64; off <<= 1) c += __shfl_xor(c, off);
        chi = c;
    }
    u64 lo = tmin, hi = T;
    while (chi > 192) {
        u64 mid = (lo + hi) >> 1;
        int c = 0;
#pragma unroll
        for (int t = 0; t < 16; ++t) c += (K[t] < mid) ? 1 : 0;
#pragma unroll
        for (int off = 1; off < 64; off <<= 1) c += __shfl_xor(c, off);
        if (c >= 101) { hi = mid; chi = c; } else lo = mid;
    }
    T = hi;
    const int n = chi;                   // 101 <= n <= 192

    // compact candidates < T via wave prefix-scan
    int myc_n = 0;
#pragma unroll
    for (int t = 0; t < 16; ++t) myc_n += (K[t] < T) ? 1 : 0;
    int sc = myc_n;
#pragma unroll
    for (int off = 1; off < 64; off <<= 1) {
        int v = __shfl_up(sc, off);
        if (lane >= off) sc += v;
    }
    int pos = sc - myc_n;
#pragma unroll
    for (int t = 0; t < 16; ++t) {
        if (K[t] < T) cand[w][pos++] = K[t];
    }
    if (lane == 0) cand[w][n] = ~0ULL;   // sentinel for b128 pair tail
    __syncthreads();

    // exact ranks within compacted set (pairs via b128)
    u64 myc[3]; int rk[3];
#pragma unroll
    for (int q = 0; q < 3; ++q) {
        int i = lane + q * 64;
        myc[q] = (i < n) ? cand[w][i] : ~0ULL;
        rk[q] = 0;
    }
    {
        const ulonglong2* c2 = (const ulonglong2*)&cand[w][0];
        const int half = (n + 1) >> 1;
        for (int jj = 0; jj < half; ++jj) {
            ulonglong2 kk = c2[jj];
#pragma unroll
            for (int q = 0; q < 3; ++q) {
                rk[q] += (kk.x < myc[q]) ? 1 : 0;
                rk[q] += (kk.y < myc[q]) ? 1 : 0;
            }
        }
    }

    // write ranks 1..100 (float4) to global AND LDS (aliasing cand[w] -
    // wave-private region; within-wave LDS ops are ordered)
    const int rowbase = row & ~1023;
    float4* nd4w = (float4*)&cand[w][0];
#pragma unroll
    for (int q = 0; q < 3; ++q) {
        int i = lane + q * 64;
        if (i < n) {
            int r = rk[q];
            if (r >= 1 && r <= 100) {
                int slot = r - 1;
                unsigned j = (unsigned)(myc[q] & 1023u);
                idx_out[row * 100 + slot] = rowbase + (int)j;
                float4 pj = vps[j];
                float dx = pj.x - xi, dy = pj.y - yi, dz = pj.z - zi;
                float nrm = sqrtf(__fadd_rn(__fadd_rn(__fmul_rn(dx, dx),
                                                      __fmul_rn(dy, dy)),
                                            __fmul_rn(dz, dz)));
                float inv = 1.0f / fmaxf(nrm, 1e-12f);
                float4 nv = make_float4(dx * inv, dy * inv, dz * inv, 0.0f);
                nd_out[row * 100 + slot] = nv;
                nd4w[slot] = nv;
            }
        }
    }
    __syncthreads();

    // ---- fused surface conv for the block's 4 rows ----
    const int d = tid & 127;
    float lx = dl[d], ly = dl[128 + d], lz = dl[256 + d];
    float li = 1.0f / fmaxf(sqrtf((lx * lx + ly * ly) + lz * lz), 1e-12f);
    lx *= li; ly *= li; lz *= li;
    float mx = dm[d], my = dm[128 + d], mz = dm[256 + d];
    float mi = 1.0f / fmaxf(sqrtf((mx * mx + my * my) + mz * mz), 1e-12f);
    mx *= mi; my *= mi; mz *= mi;
    float gx = dg[d], gy = dg[128 + d], gz = dg[256 + d];
    float gi = 1.0f / fmaxf(sqrtf((gx * gx + gy * gy) + gz * gz), 1e-12f);
    gx *= gi; gy *= gi; gz *= gi;

#pragma unroll
    for (int p = 0; p < 2; ++p) {
        int rr = (tid >> 7) + 2 * p;     // wave-uniform
        const float4* ns = (const float4*)&cand[rr][0];
        float ml = -1e30f, mm = -1e30f, mg = -1e30f;
        int k = 0;
        for (; k < 5; ++k) {
            float4 v = ns[k];
            ml = fmaxf(ml, (v.x * lx + v.y * ly) + v.z * lz);
            mm = fmaxf(mm, (v.x * mx + v.y * my) + v.z * mz);
            mg = fmaxf(mg, (v.x * gx + v.y * gy) + v.z * gz);
        }
        for (; k < 20; ++k) {
            float4 v = ns[k];
            mm = fmaxf(mm, (v.x * mx + v.y * my) + v.z * mz);
            mg = fmaxf(mg, (v.x * gx + v.y * gy) + v.z * gz);
        }
        for (; k < 100; ++k) {
            float4 v = ns[k];
            mg = fmaxf(mg, (v.x * gx + v.y * gy) + v.z * gz);
        }
        int orow = row0 + rr;
        raw_l[orow * 128 + d] = fmaxf(ml, 0.0f);
        raw_m[orow * 128 + d] = fmaxf(mm, 0.0f);
        raw_g[orow * 128 + d] = fmaxf(mg, 0.0f);
    }
}

// ---------------------------------------------------------------------------
// Kernel 2: BN partial sums: 32 blocks per tensor, 128 rows each, coalesced,
// fp64, deterministic. Layout: p[blk*256+c]=sum, p[blk*256+128+c]=sumsq.
// ---------------------------------------------------------------------------
__global__ __launch_bounds__(256) void bnsum_kernel(
    const float* s0, double* p0,
    const float* s1, double* p1,
    const float* s2, double* p2)
{
    const int t = blockIdx.x >> 5;
    const int blk = blockIdx.x & 31;
    const float* src = (t == 0) ? s0 : (t == 1) ? s1 : s2;
    double* p = (t == 0) ? p0 : (t == 1) ? p1 : p2;
    const int tid = threadIdx.x;
    const int c = tid & 127, seg = tid >> 7;    // 2 segs x 64 rows
    const float* q = src + ((size_t)blk * 128 + seg * 64) * 128 + c;
    double s = 0.0, ss = 0.0;
    for (int r = 0; r < 64; ++r) { float v = q[r * 128]; s += v; ss += (double)v * v; }
    __shared__ double Ls[2][128], Lq[2][128];
    Ls[seg][c] = s; Lq[seg][c] = ss;
    __syncthreads();
    if (tid < 128) {
        p[blk * 256 + c]       = Ls[0][c] + Ls[1][c];
        p[blk * 256 + 128 + c] = Lq[0][c] + Lq[1][c];
    }
}

// st from partials: a = g/sqrt(var+eps), b2 = e - m*a (fp64, deterministic)
__device__ __forceinline__ void compute_st(const double* __restrict__ p,
                                           const float* __restrict__ g,
                                           const float* __restrict__ e,
                                           float* stA, float* stB,
                                           int tid, int nthreads)
{
    for (int c = tid; c < 128; c += nthreads) {
        double S = 0.0, Q = 0.0;
#pragma unroll
        for (int bb = 0; bb < 32; ++bb) { S += p[bb * 256 + c]; Q += p[bb * 256 + 128 + c]; }
        double m = S * (1.0 / 4096.0);
        double var = Q * (1.0 / 4096.0) - m * m;
        double a = (double)g[c] / sqrt(var + 1e-5);
        stA[c] = (float)a;
        stB[c] = (float)((double)e[c] - m * a);
    }
}

// ---------------------------------------------------------------------------
// Kernel 3: dual-job GEMM (CIN=128). Thread = 4 rows x 2 cols (cols 2o,2o+1)
// -> 2 FMAs per LDS-broadcast float, halving the per-CU LDS-pipe pressure
// that pinned all C=1 variants at ~35% VALUBusy. Block = 16 rows x 128 cols,
// 256 threads; grid (256 rowtiles, 2 coltiles, jobs). W read as coalesced
// float2, output stored as float2. BN applied during staging (fp64
// compute_st, same expression as before).
// ---------------------------------------------------------------------------
__global__ __launch_bounds__(256) void gemm2_kernel(
    const float* __restrict__ Aa, const double* __restrict__ pa,
    const float* __restrict__ ga, const float* __restrict__ ea,
    const float* __restrict__ Wa, const float* __restrict__ ba, float* __restrict__ outa,
    const float* __restrict__ Ab, const double* __restrict__ pb,
    const float* __restrict__ gb, const float* __restrict__ eb,
    const float* __restrict__ Wb, const float* __restrict__ bb, float* __restrict__ outb)
{
    const int job = blockIdx.z;
    const float* __restrict__ A = job ? Ab : Aa;
    const double* __restrict__ p = job ? pb : pa;
    const float* __restrict__ g = job ? gb : ga;
    const float* __restrict__ e = job ? eb : ea;
    const float* __restrict__ W = job ? Wb : Wa;
    const float* __restrict__ bias = job ? bb : ba;
    float* __restrict__ out = job ? outb : outa;

    __shared__ float stA[128], stB[128];
    __shared__ float As[16 * 128];               // 8 KB
    const int tid = threadIdx.x;
    const int r0 = blockIdx.x * 16;

    compute_st(p, g, e, stA, stB, tid, 256);
    __syncthreads();

    // stage 16x128 BN-applied rows, float4-vectorized
    {
        const float4* A4 = (const float4*)(A + (size_t)r0 * 128);
        float4* As4 = (float4*)As;
        for (int t = tid; t < 16 * 32; t += 256) {
            int c = (t & 31) * 4;
            float4 v = A4[t];
            float4 o4;
            o4.x = fmaxf(fmaf(stA[c + 0], v.x, stB[c + 0]), 0.0f);
            o4.y = fmaxf(fmaf(stA[c + 1], v.y, stB[c + 1]), 0.0f);
            o4.z = fmaxf(fmaf(stA[c + 2], v.z, stB[c + 2]), 0.0f);
            o4.w = fmaxf(fmaf(stA[c + 3], v.w, stB[c + 3]), 0.0f);
            As4[t] = o4;
        }
    }
    __syncthreads();

    const int o = tid & 63;              // col-pair index
    const int h = tid >> 6;              // rowgroup: rows h*4 .. h*4+3
    const int cb = blockIdx.y * 128 + 2 * o;
    const float* Wp = W + cb;

    float acc0[4], acc1[4];
    const float2 bz = *(const float2*)&bias[cb];
#pragma unroll
    for (int r = 0; r < 4; ++r) { acc0[r] = bz.x; acc1[r] = bz.y; }

    for (int k0 = 0; k0 < 128; k0 += 4) {
        float4 a[4];
#pragma unroll
        for (int r = 0; r < 4; ++r)
            a[r] = *(const float4*)&As[(h * 4 + r) * 128 + k0];
        float2 w[4];
#pragma unroll
        for (int q = 0; q < 4; ++q) w[q] = *(const float2*)&Wp[(k0 + q) * 256];
#pragma unroll
        for (int r = 0; r < 4; ++r) {
            acc0[r] += a[r].x * w[0].x + a[r].y * w[1].x + a[r].z * w[2].x + a[r].w * w[3].x;
            acc1[r] += a[r].x * w[0].y + a[r].y * w[1].y + a[r].z * w[2].y + a[r].w * w[3].y;
        }
    }
#pragma unroll
    for (int r = 0; r < 4; ++r)
        *(float2*)&out[(size_t)(r0 + h * 4 + r) * 256 + cb] = make_float2(acc0[r], acc1[r]);
}

// ---------------------------------------------------------------------------
// Kernel 4: conv-layer apply, 1 row per 128-thread block, up to 2 jobs via
// blockIdx.y. nd (float4) / idx reads wave-uniform -> scalar loads.
// ---------------------------------------------------------------------------
__global__ __launch_bounds__(128) void layer_kernel(
    const float4* __restrict__ nd, const int* __restrict__ idxbuf,
    const float* dir0, const float* fo0, float* out0, int K0,
    const float* dir1, const float* fo1, float* out1, int K1)
{
    const int job = blockIdx.y;
    const float* dirs = job ? dir1 : dir0;
    const float* fo = job ? fo1 : fo0;
    float* out = job ? out1 : out0;
    const int K = job ? K1 : K0;

    const int d = threadIdx.x;
    const int row = blockIdx.x;

    float dx = dirs[d], dy = dirs[128 + d], dz = dirs[256 + d];
    float di = 1.0f / fmaxf(sqrtf((dx * dx + dy * dy) + dz * dz), 1e-12f);
    dx *= di; dy *= di; dz *= di;

    const float4* ns = nd + (size_t)row * 100;
    const int* ib = idxbuf + (size_t)row * 100;

    float acc = -1e30f;
    for (int k = 0; k < K; ++k) {
        float4 v = ns[k];
        int ix = ib[k];
        float th = fmaxf((v.x * dx + v.y * dy) + v.z * dz, 0.0f);
        float fs = fo[ix * 256 + 128 + d];
        acc = fmaxf(acc, th * fs);
    }
    out[row * 128 + d] = fo[row * 256 + d] + acc;
}

// ---------------------------------------------------------------------------
// Kernel 5: final GEMM (CIN=384). Same C=2 structure as gemm2: thread =
// 4 rows x 2 cols, block = 16 rows x 128 cols, grid (256, 2). BN affines for
// 3 segments derived in-kernel; staging float4-vectorized; final relu.
// LDS 24 KB + 3 KB.
// ---------------------------------------------------------------------------
__global__ __launch_bounds__(256) void gemmf_kernel(
    const float* __restrict__ A0, const double* __restrict__ p0,
    const float* __restrict__ g0, const float* __restrict__ e0,
    const float* __restrict__ A1, const double* __restrict__ p1,
    const float* __restrict__ g1, const float* __restrict__ e1,
    const float* __restrict__ A2, const double* __restrict__ p2,
    const float* __restrict__ g2, const float* __restrict__ e2,
    const float* __restrict__ W, const float* __restrict__ bias, float* __restrict__ out)
{
    __shared__ float stA[384], stB[384];
    __shared__ float As[16 * 384];               // 24 KB
    const int tid = threadIdx.x;
    const int r0 = blockIdx.x * 16;

    compute_st(p0, g0, e0, stA,       stB,       tid, 256);
    compute_st(p1, g1, e1, stA + 128, stB + 128, tid, 256);
    compute_st(p2, g2, e2, stA + 256, stB + 256, tid, 256);
    __syncthreads();

    // stage 16x384 BN-applied rows, float4-vectorized (96 float4 per row)
    {
        float4* As4 = (float4*)As;
        for (int t = tid; t < 16 * 96; t += 256) {
            int r = t / 96, c4 = t - r * 96;
            int seg = c4 >> 5, cc4 = c4 & 31;
            const float* A = (seg == 0) ? A0 : (seg == 1) ? A1 : A2;
            float4 v = *(const float4*)&A[(size_t)(r0 + r) * 128 + cc4 * 4];
            int c = c4 * 4;
            float4 o4;
            o4.x = fmaxf(fmaf(stA[c + 0], v.x, stB[c + 0]), 0.0f);
            o4.y = fmaxf(fmaf(stA[c + 1], v.y, stB[c + 1]), 0.0f);
            o4.z = fmaxf(fmaf(stA[c + 2], v.z, stB[c + 2]), 0.0f);
            o4.w = fmaxf(fmaf(stA[c + 3], v.w, stB[c + 3]), 0.0f);
            As4[t] = o4;
        }
    }
    __syncthreads();

    const int o = tid & 63;
    const int h = tid >> 6;
    const int cb = blockIdx.y * 128 + 2 * o;
    const float* Wp = W + cb;

    float acc0[4], acc1[4];
    const float2 bz = *(const float2*)&bias[cb];
#pragma unroll
    for (int r = 0; r < 4; ++r) { acc0[r] = bz.x; acc1[r] = bz.y; }

    for (int k0 = 0; k0 < 384; k0 += 4) {
        float4 a[4];
#pragma unroll
        for (int r = 0; r < 4; ++r)
            a[r] = *(const float4*)&As[(h * 4 + r) * 384 + k0];
        float2 w[4];
#pragma unroll
        for (int q = 0; q < 4; ++q) w[q] = *(const float2*)&Wp[(k0 + q) * 256];
#pragma unroll
        for (int r = 0; r < 4; ++r) {
            acc0[r] += a[r].x * w[0].x + a[r].y * w[1].x + a[r].z * w[2].x + a[r].w * w[3].x;
            acc1[r] += a[r].x * w[0].y + a[r].y * w[1].y + a[r].z * w[2].y + a[r].w * w[3].y;
        }
    }
#pragma unroll
    for (int r = 0; r < 4; ++r)
        *(float2*)&out[(size_t)(r0 + h * 4 + r) * 256 + cb] =
            make_float2(fmaxf(acc0[r], 0.0f), fmaxf(acc1[r], 0.0f));
}

// ---------------------------------------------------------------------------
extern "C" void kernel_launch(void* const* d_in, const int* in_sizes, int n_in,
                              void* d_out, int out_size, void* d_ws, size_t ws_size,
                              hipStream_t stream)
{
    (void)in_sizes; (void)n_in; (void)out_size; (void)ws_size;

    const float* verts   = (const float*)d_in[0];
    const float* dirs_l  = (const float*)d_in[1];
    const float* dirs_m0 = (const float*)d_in[2];
    const float* W_m1    = (const float*)d_in[3];
    const float* b_m1    = (const float*)d_in[4];
    const float* dirs_m1 = (const float*)d_in[5];
    const float* dirs_g0 = (const float*)d_in[6];
    const float* W_g1    = (const float*)d_in[7];
    const float* b_g1    = (const float*)d_in[8];
    const float* dirs_g1 = (const float*)d_in[9];
    const float* W_g2    = (const float*)d_in[10];
    const float* b_g2    = (const float*)d_in[11];
    const float* dirs_g2 = (const float*)d_in[12];
    const float* g_l  = (const float*)d_in[13]; const float* be_l  = (const float*)d_in[14];
    const float* g_m0 = (const float*)d_in[15]; const float* be_m0 = (const float*)d_in[16];
    const float* g_m1 = (const float*)d_in[17]; const float* be_m1 = (const float*)d_in[18];
    const float* g_g0 = (const float*)d_in[19]; const float* be_g0 = (const float*)d_in[20];
    const float* g_g1 = (const float*)d_in[21]; const float* be_g1 = (const float*)d_in[22];
    const float* g_g2 = (const float*)d_in[23]; const float* be_g2 = (const float*)d_in[24];
    const float* W_down = (const float*)d_in[25];
    const float* b_down = (const float*)d_in[26];

    char* ws = (char*)d_ws;
    const size_t MB = 1 << 20;
    int*    idx100 = (int*)   (ws + 0);               // 1.64 MB
    double* p_l    = (double*)(ws + 0x1A0000);        // 6 x 64 KB fp64 partials
    double* p_m0   = p_l  + 8192;
    double* p_m1   = p_m0 + 8192;
    double* p_g0   = p_m1 + 8192;
    double* p_g1   = p_g0 + 8192;
    double* p_g2   = p_g1 + 8192;
    float4* nd100  = (float4*)(ws + 2 * MB);          // 6.55 MB (stride-4)
    float* raw_l  = (float*)(ws +  9 * MB);           // 2 MB each
    float* raw_m0 = (float*)(ws + 11 * MB);
    float* raw_g0 = (float*)(ws + 13 * MB);
    float* raw_m1 = (float*)(ws + 15 * MB);
    float* raw_g1 = (float*)(ws + 17 * MB);
    float* raw_g2 = (float*)(ws + 19 * MB);
    float* fo_m   = (float*)(ws + 21 * MB);           // 4 MB each
    float* fo_g   = (float*)(ws + 25 * MB);
    float* fo_g2  = (float*)(ws + 29 * MB);

    // L1. KNN + nd + fused surface convs (k=5/20/100)
    knnsurf_kernel<<<1024, 256, 0, stream>>>(verts, idx100, nd100,
                                             dirs_l, dirs_m0, dirs_g0,
                                             raw_l, raw_m0, raw_g0);
    // L2. BN partials for l, m0, g0
    bnsum_kernel<<<96, 256, 0, stream>>>(raw_l, p_l, raw_m0, p_m0, raw_g0, p_g0);
    // L3. fo_m = bn_relu(raw_m0) @ W_m1 ; fo_g = bn_relu(raw_g0) @ W_g1
    gemm2_kernel<<<dim3(256, 2, 2), 256, 0, stream>>>(
        raw_m0, p_m0, g_m0, be_m0, W_m1, b_m1, fo_m,
        raw_g0, p_g0, g_g0, be_g0, W_g1, b_g1, fo_g);
    // L4. conv-layer apply (m1: K=20, g1: K=100)
    layer_kernel<<<dim3(4096, 2), 128, 0, stream>>>(nd100, idx100,
                                                    dirs_m1, fo_m, raw_m1, 20,
                                                    dirs_g1, fo_g, raw_g1, 100);
    // L5. BN partials for m1, g1
    bnsum_kernel<<<64, 256, 0, stream>>>(raw_m1, p_m1, raw_g1, p_g1, raw_g1, p_g1);
    // L6. fo_g2 = bn_relu(raw_g1) @ W_g2
    gemm2_kernel<<<dim3(256, 2, 1), 256, 0, stream>>>(
        raw_g1, p_g1, g_g1, be_g1, W_g2, b_g2, fo_g2,
        raw_g1, p_g1, g_g1, be_g1, W_g2, b_g2, fo_g2);
    // L7. conv-layer apply (g2: K=100)
    layer_kernel<<<dim3(4096, 1), 128, 0, stream>>>(nd100, idx100,
                                                    dirs_g2, fo_g2, raw_g2, 100,
                                                    dirs_g2, fo_g2, raw_g2, 100);
    // L8. BN partials for g2
    bnsum_kernel<<<32, 256, 0, stream>>>(raw_g2, p_g2, raw_g2, p_g2, raw_g2, p_g2);
    // L9. final: relu(concat(bn_relu each) @ W_down + b_down) -> fp32 out
    gemmf_kernel<<<dim3(256, 2), 256, 0, stream>>>(raw_l, p_l, g_l, be_l,
                                                   raw_m1, p_m1, g_m1, be_m1,
                                                   raw_g2, p_g2, g_g2, be_g2,
                                                   W_down, b_down, (float*)d_out);
}